// Round 8
// baseline (832.658 us; speedup 1.0000x reference)
//
#include <hip/hip_runtime.h>
#include <stdint.h>

#define NV 2097152
#define MC 1048576
#define EE 6291456
#define TT 10

#define CHUNK 8192
#define NBLK 768        // EE / CHUNK
#define FBK 1024        // check blocks: 1024 checks = 6144 positions each
#define CPB2 1024
#define CSEG2 6144
#define PBK 512         // place1 blocks: 2048 checks = 12288 positions
#define PSEG 12288
#define FG 512          // forward producer groups: 4096 vars = 12288 edges
#define GSEG 12288
#define VBK 256         // var blocks: 8192 vars = 24576 edge-nibbles each
#define VSEG 24576

// ---------------- cursor init: gcur[b] = b*12288 for both bin passes ----------------
__global__ __launch_bounds__(512) void initcur_kernel(uint32_t* __restrict__ gcur) {
    int i = blockIdx.x * 512 + threadIdx.x;     // grid 2x512 -> 1024
    gcur[i] = (uint32_t)(i & 511) * 12288u;
}

// ---------------- bin1: bucket edges by place-block, destination-sorted writes ----------------
__global__ __launch_bounds__(512) void bin1_kernel(const int* __restrict__ chk_idx,
                                                   uint32_t* __restrict__ gcurA,
                                                   uint32_t* __restrict__ im1_e,
                                                   uint16_t* __restrict__ im1_c) {
    __shared__ uint32_t cnt[4][512];   // 8 KB, 4-way wave-pair replicated
    __shared__ uint32_t scanv[512];    // 2 KB
    __shared__ uint32_t adj[512];      // 2 KB
    __shared__ uint32_t sA[CHUNK];     // 32 KB: (b<<23)|e
    __shared__ uint16_t sB[CHUNK];     // 16 KB: clow
    const int tid = threadIdx.x;
    const int rep = tid >> 7;          // 0..3
    const int base = blockIdx.x * CHUNK;
    cnt[0][tid] = 0; cnt[1][tid] = 0; cnt[2][tid] = 0; cnt[3][tid] = 0;
    __syncthreads();
    int4 cc4[4];                       // 16 entries/thread
#pragma unroll
    for (int k = 0; k < 4; ++k) cc4[k] = ((const int4*)chk_idx)[(base >> 2) + tid + 512 * k];
    uint32_t br[16];                   // (b<<13)|rank
#pragma unroll
    for (int k = 0; k < 4; ++k) {
        int cv[4] = {cc4[k].x, cc4[k].y, cc4[k].z, cc4[k].w};
#pragma unroll
        for (int ii = 0; ii < 4; ++ii) {
            uint32_t b = (uint32_t)cv[ii] >> 11;
            uint32_t r = atomicAdd(&cnt[rep][b], 1u);
            br[k * 4 + ii] = (b << 13) | r;
        }
    }
    __syncthreads();
    uint32_t c0 = cnt[0][tid], c1 = cnt[1][tid], c2 = cnt[2][tid], c3 = cnt[3][tid];
    uint32_t tot = c0 + c1 + c2 + c3;
    scanv[tid] = tot;
    __syncthreads();
    for (int d = 1; d < 512; d <<= 1) {
        uint32_t a0 = (tid >= d) ? scanv[tid - d] : 0u;
        __syncthreads();
        scanv[tid] += a0;
        __syncthreads();
    }
    uint32_t excl = scanv[tid] - tot;
    adj[tid] = atomicAdd(&gcurA[tid], tot) - excl;
    __syncthreads();
    scanv[tid] = excl;
    cnt[0][tid] = 0; cnt[1][tid] = c0; cnt[2][tid] = c0 + c1; cnt[3][tid] = c0 + c1 + c2;
    __syncthreads();
    // pass B: scatter into LDS staging at sorted slot
#pragma unroll
    for (int k = 0; k < 4; ++k) {
        int cv[4] = {cc4[k].x, cc4[k].y, cc4[k].z, cc4[k].w};
#pragma unroll
        for (int ii = 0; ii < 4; ++ii) {
            uint32_t v = br[k * 4 + ii];
            uint32_t b = v >> 13;
            uint32_t r = v & 8191u;
            uint32_t j = scanv[b] + cnt[rep][b] + r;
            uint32_t e = (uint32_t)(base + (tid + 512 * k) * 4 + ii);
            sA[j] = (b << 23) | e;
            sB[j] = (uint16_t)((uint32_t)cv[ii] & 2047u);
        }
    }
    __syncthreads();
    // pass C: coalesced run writes
    for (int k = 0; k < 16; ++k) {
        int j = tid + 512 * k;
        uint32_t v = sA[j];
        uint32_t b = v >> 23;
        uint32_t addr = adj[b] + (uint32_t)j;
        im1_e[addr] = v & 0x7FFFFFu;
        im1_c[addr] = sB[j];
    }
}

// ---------------- place1 + ba fused: chk_edges, b1rank (half-split), runcntB ----------------
__global__ __launch_bounds__(512) void place1_kernel(const uint32_t* __restrict__ im1_e,
                                                     const uint16_t* __restrict__ im1_c,
                                                     uint32_t* __restrict__ chk_edges,
                                                     uint8_t* __restrict__ b1rank,
                                                     uint32_t* __restrict__ runcntB) {
    __shared__ uint32_t win[PSEG];       // 48 KB
    __shared__ uint32_t ccnt[2048];      // 8 KB
    __shared__ uint32_t cntB[2][VBK];    // 2 KB
    const int tid = threadIdx.x, blk = blockIdx.x;
    for (int j = tid; j < 2048; j += 512) ccnt[j] = 0;
    if (tid < 2 * VBK) ((uint32_t*)cntB)[tid] = 0;
    __syncthreads();
    const size_t cb = (size_t)blk * PSEG;
    for (int k = 0; k < 6; ++k) {
        int j0 = (tid + 512 * k) * 4;
        const uint4 e4 = *(const uint4*)&im1_e[cb + j0];
        const ushort4 c4 = *(const ushort4*)&im1_c[cb + j0];
        uint32_t s;
        s = atomicAdd(&ccnt[c4.x], 1u); win[c4.x * 6 + s] = e4.x;
        s = atomicAdd(&ccnt[c4.y], 1u); win[c4.y * 6 + s] = e4.y;
        s = atomicAdd(&ccnt[c4.z], 1u); win[c4.z * 6 + s] = e4.z;
        s = atomicAdd(&ccnt[c4.w], 1u); win[c4.w * 6 + s] = e4.w;
    }
    __syncthreads();
    for (int j = tid; j < PSEG; j += 512) chk_edges[cb + j] = win[j];
    for (int k = 0; k < PSEG / 512; ++k) {
        int lp = tid + 512 * k;
        uint32_t e = win[lp];
        uint32_t bB = (e / 3u) >> 13;
        int half = (lp >= CSEG2) ? 1 : 0;
        uint32_t r = atomicAdd(&cntB[half][bB], 1u);
        b1rank[cb + lp] = (uint8_t)r;
    }
    __syncthreads();
    if (tid < VBK) {
        runcntB[(size_t)tid * 1024 + blk * 2 + 0] = cntB[0][tid];
        runcntB[(size_t)tid * 1024 + blk * 2 + 1] = cntB[1][tid];
    }
}

// ---------------- bin2: bucket (position -> edge) by var-group, destination-sorted ----------------
__global__ __launch_bounds__(512) void bin2_kernel(const uint32_t* __restrict__ chk_edges,
                                                   uint32_t* __restrict__ gcurB,
                                                   uint32_t* __restrict__ im2_pay,
                                                   uint16_t* __restrict__ im2_el) {
    __shared__ uint32_t cnt[4][512];
    __shared__ uint32_t scanv[512];
    __shared__ uint32_t adj[512];
    __shared__ uint32_t sA[CHUNK];     // (vb<<13)|pos_local
    __shared__ uint16_t sB[CHUNK];     // elow
    const int tid = threadIdx.x;
    const int rep = tid >> 7;
    const int base = blockIdx.x * CHUNK;
    cnt[0][tid] = 0; cnt[1][tid] = 0; cnt[2][tid] = 0; cnt[3][tid] = 0;
    __syncthreads();
    uint4 ee4[4];
#pragma unroll
    for (int k = 0; k < 4; ++k) ee4[k] = ((const uint4*)chk_edges)[(base >> 2) + tid + 512 * k];
    uint32_t br[16];
#pragma unroll
    for (int k = 0; k < 4; ++k) {
        uint32_t ev[4] = {ee4[k].x, ee4[k].y, ee4[k].z, ee4[k].w};
#pragma unroll
        for (int ii = 0; ii < 4; ++ii) {
            uint32_t vb = ev[ii] / 12288u;
            uint32_t r = atomicAdd(&cnt[rep][vb], 1u);
            br[k * 4 + ii] = (vb << 13) | r;
        }
    }
    __syncthreads();
    uint32_t c0 = cnt[0][tid], c1 = cnt[1][tid], c2 = cnt[2][tid], c3 = cnt[3][tid];
    uint32_t tot = c0 + c1 + c2 + c3;
    scanv[tid] = tot;
    __syncthreads();
    for (int d = 1; d < 512; d <<= 1) {
        uint32_t a0 = (tid >= d) ? scanv[tid - d] : 0u;
        __syncthreads();
        scanv[tid] += a0;
        __syncthreads();
    }
    uint32_t excl = scanv[tid] - tot;
    adj[tid] = atomicAdd(&gcurB[tid], tot) - excl;
    __syncthreads();
    scanv[tid] = excl;
    cnt[0][tid] = 0; cnt[1][tid] = c0; cnt[2][tid] = c0 + c1; cnt[3][tid] = c0 + c1 + c2;
    __syncthreads();
#pragma unroll
    for (int k = 0; k < 4; ++k) {
        uint32_t ev[4] = {ee4[k].x, ee4[k].y, ee4[k].z, ee4[k].w};
#pragma unroll
        for (int ii = 0; ii < 4; ++ii) {
            uint32_t v = br[k * 4 + ii];
            uint32_t vb = v >> 13;
            uint32_t r = v & 8191u;
            uint32_t j = scanv[vb] + cnt[rep][vb] + r;
            uint32_t pl = (uint32_t)((tid + 512 * k) * 4 + ii);
            sA[j] = (vb << 13) | pl;
            sB[j] = (uint16_t)(ev[ii] - vb * 12288u);
        }
    }
    __syncthreads();
    for (int k = 0; k < 16; ++k) {
        int j = tid + 512 * k;
        uint32_t v = sA[j];
        uint32_t vb = v >> 13;
        uint32_t pos = (uint32_t)base + (v & 8191u);
        uint32_t c = pos / 6u;
        uint32_t s = pos - c * 6u;
        uint32_t addr = adj[vb] + (uint32_t)j;
        im2_pay[addr] = (c << 3) | s;
        im2_el[addr] = sB[j];
    }
}

// ---------------- place2 + fa fused: dest, f1rank, runcntF ----------------
__global__ __launch_bounds__(512) void place2_kernel(const uint32_t* __restrict__ im2_pay,
                                                     const uint16_t* __restrict__ im2_el,
                                                     uint32_t* __restrict__ dest,
                                                     uint8_t* __restrict__ f1rank,
                                                     uint32_t* __restrict__ runcntF) {
    __shared__ uint32_t win2[GSEG];      // 48 KB
    __shared__ uint32_t cntF[FBK];       // 4 KB
    const int tid = threadIdx.x, g = blockIdx.x;
    cntF[tid] = 0; cntF[tid + 512] = 0;
    __syncthreads();
    const size_t gb = (size_t)g * GSEG;
    for (int k = 0; k < 6; ++k) {
        int j0 = (tid + 512 * k) * 4;
        const uint4 p4 = *(const uint4*)&im2_pay[gb + j0];
        const ushort4 e4 = *(const ushort4*)&im2_el[gb + j0];
        win2[e4.x] = p4.x; win2[e4.y] = p4.y; win2[e4.z] = p4.z; win2[e4.w] = p4.w;
    }
    __syncthreads();
    for (int j = tid; j < GSEG; j += 512) dest[gb + j] = win2[j];
    for (int k = 0; k < GSEG / 512; ++k) {
        int le = tid + 512 * k;
        uint32_t b = (win2[le] >> 3) >> 10;
        uint32_t r = atomicAdd(&cntF[b], 1u);
        f1rank[gb + le] = (uint8_t)r;
    }
    __syncthreads();
    runcntF[(size_t)tid * FG + g] = cntF[tid];
    runcntF[(size_t)(tid + 512) * FG + g] = cntF[tid + 512];
}

// ---------------- scans ----------------
__global__ void scanF_kernel(const uint32_t* __restrict__ runcntF,
                             uint32_t* __restrict__ f1base) {
    int b = blockIdx.x * 512 + threadIdx.x;      // grid 2x512 -> 1024 buckets
    uint32_t acc = (uint32_t)b * CSEG2;
    for (int g = 0; g < FG; ++g) {
        f1base[(size_t)g * FBK + b] = acc;
        acc += runcntF[(size_t)b * FG + g];
    }
}

__global__ void scanB_kernel(const uint32_t* __restrict__ runcntB,
                             uint32_t* __restrict__ b1base) {
    int bB = threadIdx.x;                        // 1 block x 256
    uint32_t acc = (uint32_t)bB * VSEG;
    for (int blk2 = 0; blk2 < 1024; ++blk2) {
        b1base[(size_t)blk2 * VBK + bB] = acc;
        acc += runcntB[(size_t)bB * 1024 + blk2];
    }
}

// ---------------- fb: forward sorted tables (f2pos, bidxF, lvF, goffF) ----------------
__global__ __launch_bounds__(512) void fb_kernel(const uint32_t* __restrict__ dest,
                                                 const uint8_t* __restrict__ f1rank,
                                                 const uint32_t* __restrict__ runcntF,
                                                 const uint32_t* __restrict__ f1base,
                                                 uint32_t* __restrict__ goffF,
                                                 uint16_t* __restrict__ f2pos,
                                                 uint16_t* __restrict__ bidxF,
                                                 uint16_t* __restrict__ lvF) {
    __shared__ uint32_t flb[FBK];        // 4 KB
    __shared__ uint32_t rowf[FBK];       // 4 KB
    __shared__ uint32_t sortv[GSEG];     // 48 KB
    const int tid = threadIdx.x, g = blockIdx.x;
    uint32_t c0 = runcntF[(size_t)tid * FG + g];
    uint32_t c1 = runcntF[(size_t)(tid + 512) * FG + g];
    flb[tid] = c0; flb[tid + 512] = c1;
    rowf[tid] = f1base[(size_t)g * FBK + tid];
    rowf[tid + 512] = f1base[(size_t)g * FBK + tid + 512];
    __syncthreads();
    for (int d = 1; d < FBK; d <<= 1) {
        uint32_t a0 = (tid >= d) ? flb[tid - d] : 0u;
        uint32_t a1 = flb[tid + 512 - d];
        __syncthreads();
        flb[tid] += a0; flb[tid + 512] += a1;
        __syncthreads();
    }
    flb[tid] -= c0; flb[tid + 512] -= c1;
    __syncthreads();
    goffF[(size_t)g * FBK + tid] = rowf[tid] - flb[tid];
    goffF[(size_t)g * FBK + tid + 512] = rowf[tid + 512] - flb[tid + 512];
    const size_t gb = (size_t)g * GSEG;
    // round 1: f2pos + bidxF
    for (int k = 0; k < GSEG / 512; ++k) {
        int le = tid + 512 * k;
        uint32_t d = dest[gb + le];
        uint32_t r = f1rank[gb + le];
        uint32_t c = d >> 3;
        uint32_t b = c >> 10;
        uint32_t pl = c * 6u + (d & 7u) - b * CSEG2;
        sortv[flb[b] + r] = (b << 14) | pl;
    }
    __syncthreads();
    for (int k = 0; k < GSEG / 512; ++k) {
        int j = tid + 512 * k;
        uint32_t v = sortv[j];
        uint32_t b = v >> 14;
        f2pos[rowf[b] - flb[b] + j] = (uint16_t)(v & 16383u);
        bidxF[gb + j] = (uint16_t)b;
    }
    __syncthreads();
    // round 2: lvF
    for (int k = 0; k < GSEG / 512; ++k) {
        int le = tid + 512 * k;
        uint32_t d = dest[gb + le];
        uint32_t r = f1rank[gb + le];
        uint32_t b = (d >> 3) >> 10;
        sortv[flb[b] + r] = (uint32_t)(le / 3);
    }
    __syncthreads();
    for (int k = 0; k < GSEG / 512; ++k) {
        int j = tid + 512 * k;
        lvF[gb + j] = (uint16_t)sortv[j];
    }
}

// ---------------- bb: backward sorted tables (b2pos, bidxB, lposB, goffB) ----------------
__global__ __launch_bounds__(512) void bb_kernel(const uint32_t* __restrict__ chk_edges,
                                                 const uint8_t* __restrict__ b1rank,
                                                 const uint32_t* __restrict__ runcntB,
                                                 const uint32_t* __restrict__ b1base,
                                                 uint32_t* __restrict__ goffB,
                                                 uint16_t* __restrict__ b2pos,
                                                 uint8_t* __restrict__ bidxB,
                                                 uint16_t* __restrict__ lposB) {
    __shared__ uint32_t blb[VBK];        // 1 KB
    __shared__ uint32_t rowb[VBK];       // 1 KB
    __shared__ uint32_t sortv[CSEG2];    // 24 KB
    const int tid = threadIdx.x, blk2 = blockIdx.x;
    if (tid < VBK) {
        uint32_t c0 = runcntB[(size_t)tid * 1024 + blk2];
        blb[tid] = c0;
        rowb[tid] = b1base[(size_t)blk2 * VBK + tid];
    }
    __syncthreads();
    for (int d = 1; d < VBK; d <<= 1) {
        uint32_t a0 = (tid < VBK && tid >= d) ? blb[tid - d] : 0u;
        __syncthreads();
        if (tid < VBK) blb[tid] += a0;
        __syncthreads();
    }
    if (tid < VBK) blb[tid] -= runcntB[(size_t)tid * 1024 + blk2];
    __syncthreads();
    if (tid < VBK) goffB[(size_t)blk2 * VBK + tid] = rowb[tid] - blb[tid];
    const size_t cb = (size_t)blk2 * CSEG2;
    // round 1: b2pos + bidxB
    for (int k = 0; k < CSEG2 / 512; ++k) {
        int lp = tid + 512 * k;
        uint32_t e = chk_edges[cb + lp];
        uint32_t r = b1rank[cb + lp];
        uint32_t bB = (e / 3u) >> 13;
        uint32_t elocal = e - bB * VSEG;
        sortv[blb[bB] + r] = (bB << 15) | elocal;
    }
    __syncthreads();
    for (int k = 0; k < CSEG2 / 512; ++k) {
        int j = tid + 512 * k;
        uint32_t v = sortv[j];
        uint32_t bB = v >> 15;
        b2pos[rowb[bB] - blb[bB] + j] = (uint16_t)(v & 32767u);
        bidxB[cb + j] = (uint8_t)bB;
    }
    __syncthreads();
    // round 2: lposB
    for (int k = 0; k < CSEG2 / 512; ++k) {
        int lp = tid + 512 * k;
        uint32_t e = chk_edges[cb + lp];
        uint32_t r = b1rank[cb + lp];
        uint32_t bB = (e / 3u) >> 13;
        sortv[blb[bB] + r] = (uint32_t)lp;
    }
    __syncthreads();
    for (int k = 0; k < CSEG2 / 512; ++k) {
        int j = tid + 512 * k;
        lposB[cb + j] = (uint16_t)sortv[j];
    }
}

// ---------------- per-iteration check kernel (1024 blocks, 24 KB window) ----------------
__global__ __launch_bounds__(256) void check_kernel(const float* __restrict__ finterm,
                                                    const uint16_t* __restrict__ f2pos,
                                                    uint32_t* __restrict__ einfo,
                                                    const uint16_t* __restrict__ lposB,
                                                    const uint8_t* __restrict__ bidxB,
                                                    const uint32_t* __restrict__ goffB,
                                                    uint8_t* __restrict__ binterm,
                                                    const float* __restrict__ beta,
                                                    const float* __restrict__ alpha,
                                                    const float* __restrict__ thresholds,
                                                    int t) {
    __shared__ __align__(16) float fwin[CSEG2];  // 24 KB; front 4 KB reused as ewin
    __shared__ uint32_t grow[VBK];               // 1 KB
    __shared__ float tp[8];
    uint32_t* ewin = (uint32_t*)fwin;
    const int tid = threadIdx.x, blk = blockIdx.x;
    if (tid < 8) tp[tid] = thresholds[((t > 0) ? (t - 1) : 0) * 8 + tid];
    grow[tid] = goffB[(size_t)blk * VBK + tid];
    const size_t cb = (size_t)blk * CSEG2;
    for (int k = 0; k < 6; ++k) {
        int j0 = (tid + 256 * k) * 4;
        const float4 f4 = *(const float4*)&finterm[cb + j0];
        const ushort4 p4 = *(const ushort4*)&f2pos[cb + j0];
        fwin[p4.x] = f4.x; fwin[p4.y] = f4.y; fwin[p4.z] = f4.z; fwin[p4.w] = f4.w;
    }
    __syncthreads();

    const float aPrev = (t > 0) ? alpha[t - 1] : 1.0f;
    const float b = beta[t];
    const float* thc = thresholds + t * 8;
    const float th1 = thc[1], th2 = thc[2], th3 = thc[3], th4 = thc[4];
    const float th5 = thc[5], th6 = thc[6], th7 = thc[7];
    const uint32_t signb = (b < 0.0f) ? 1u : 0u;

    uint32_t wreg[4];
    for (int i = 0; i < 4; ++i) {
        int lc = tid + 256 * i;
        uint32_t wprev = (t > 0) ? einfo[blk * CPB2 + lc] : 0u;
        float mags[6];
        uint32_t sgn[6];
        uint32_t parity = 0;
        uint64_t minkey = ~0ull;
#pragma unroll
        for (int j = 0; j < 6; ++j) {
            float p = fwin[lc * 6 + j];
            uint32_t nib = (wprev >> (4 * j)) & 15u;
            float mg0 = tp[nib & 7u];
            float c2v = (nib & 8u) ? -mg0 : mg0;
            float x = aPrev * (p - c2v);           // exact v2c reconstruction
            uint32_t s = (x < 0.0f) ? 1u : 0u;
            parity ^= s;
            sgn[j] = s;
            float mg = fabsf(x);
            mags[j] = mg;
            uint64_t key = (((uint64_t)__float_as_uint(mg)) << 3) | (uint32_t)j;
            minkey = (key < minkey) ? key : minkey;
        }
        float min1 = __uint_as_float((uint32_t)(minkey >> 3));
        uint32_t fs = (uint32_t)(minkey & 7u);
        float min2 = INFINITY;
#pragma unroll
        for (int j = 0; j < 6; ++j) {
            if ((uint32_t)j != fs) min2 = fminf(min2, mags[j]);
        }
        float m1 = fabsf(b * min1);
        float m2 = fabsf(b * min2);
        uint32_t q1 = (uint32_t)(m1 >= th1) + (uint32_t)(m1 >= th2) + (uint32_t)(m1 >= th3)
                    + (uint32_t)(m1 >= th4) + (uint32_t)(m1 >= th5) + (uint32_t)(m1 >= th6)
                    + (uint32_t)(m1 >= th7);
        uint32_t q2 = (uint32_t)(m2 >= th1) + (uint32_t)(m2 >= th2) + (uint32_t)(m2 >= th3)
                    + (uint32_t)(m2 >= th4) + (uint32_t)(m2 >= th5) + (uint32_t)(m2 >= th6)
                    + (uint32_t)(m2 >= th7);
        uint32_t w = 0;
#pragma unroll
        for (int j = 0; j < 6; ++j) {
            uint32_t neg = signb ^ parity ^ sgn[j];
            uint32_t q = ((uint32_t)j == fs) ? q2 : q1;
            w |= ((neg << 3) | q) << (4 * j);
        }
        wreg[i] = w;
    }
    __syncthreads();                 // fwin reads done; safe to alias ewin
    for (int i = 0; i < 4; ++i) {
        int lc = tid + 256 * i;
        ewin[lc] = wreg[i];
        einfo[blk * CPB2 + lc] = wreg[i];
    }
    __syncthreads();
    for (int k = 0; k < 6; ++k) {
        int j0 = (tid + 256 * k) * 4;
        const ushort4 lp4 = *(const ushort4*)&lposB[cb + j0];
        const uchar4 b4 = *(const uchar4*)&bidxB[cb + j0];
        uint32_t lp, word;
        lp = lp4.x; word = ewin[lp / 6u];
        binterm[grow[b4.x] + j0 + 0] = (uint8_t)((word >> ((lp - 6u * (lp / 6u)) * 4u)) & 15u);
        lp = lp4.y; word = ewin[lp / 6u];
        binterm[grow[b4.y] + j0 + 1] = (uint8_t)((word >> ((lp - 6u * (lp / 6u)) * 4u)) & 15u);
        lp = lp4.z; word = ewin[lp / 6u];
        binterm[grow[b4.z] + j0 + 2] = (uint8_t)((word >> ((lp - 6u * (lp / 6u)) * 4u)) & 15u);
        lp = lp4.w; word = ewin[lp / 6u];
        binterm[grow[b4.w] + j0 + 3] = (uint8_t)((word >> ((lp - 6u * (lp / 6u)) * 4u)) & 15u);
    }
}

// ---------------- per-iteration variable kernel (modes: 0 normal, 1 seed, 2 last) ----------------
__global__ __launch_bounds__(512) void var_kernel(const float* __restrict__ llr,
                                                  const uint8_t* __restrict__ binterm,
                                                  const uint16_t* __restrict__ b2pos,
                                                  const uint16_t* __restrict__ lvF,
                                                  const uint16_t* __restrict__ bidxF,
                                                  const uint32_t* __restrict__ goffF,
                                                  float* __restrict__ finterm,
                                                  const float* __restrict__ thresholds,
                                                  int t, int mode,
                                                  float* __restrict__ out) {
    __shared__ uint8_t nwin[VSEG];       // 24 KB
    __shared__ float pwin[8192];         // 32 KB
    __shared__ uint32_t growF[FBK];      // 4 KB
    __shared__ float tl[8];
    const int tid = threadIdx.x, vblk = blockIdx.x;
    if (tid < 8) tl[tid] = thresholds[t * 8 + tid];
    if (mode != 1) {
        const size_t vb = (size_t)vblk * VSEG;
        for (int k = 0; k < 12; ++k) {
            int i0 = (tid + 512 * k) * 4;
            const uchar4 n4 = *(const uchar4*)&binterm[vb + i0];
            const ushort4 p4 = *(const ushort4*)&b2pos[vb + i0];
            nwin[p4.x] = n4.x; nwin[p4.y] = n4.y; nwin[p4.z] = n4.z; nwin[p4.w] = n4.w;
        }
    }
    __syncthreads();
    for (int i = 0; i < 16; ++i) {
        int lv = tid + 512 * i;
        int v = vblk * 8192 + lv;
        float post;
        if (mode == 1) {
            post = llr[v];
        } else {
            uint32_t n0 = nwin[3 * lv], n1 = nwin[3 * lv + 1], n2 = nwin[3 * lv + 2];
            float c0 = (n0 & 8u) ? -tl[n0 & 7u] : tl[n0 & 7u];
            float c1 = (n1 & 8u) ? -tl[n1 & 7u] : tl[n1 & 7u];
            float c2 = (n2 & 8u) ? -tl[n2 & 7u] : tl[n2 & 7u];
            post = llr[v] + ((c0 + c1) + c2);      // reference summation order
        }
        pwin[lv] = post;
        if (mode == 2) {
            out[v] = (post < 0.0f) ? 1.0f : 0.0f;
            out[NV + v] = post;
            if (v == 0) out[2 * NV] = 10.0f;
        }
    }
    __syncthreads();
    if (mode != 2) {
        for (int h = 0; h < 2; ++h) {
            int g = 2 * vblk + h;
            growF[tid] = goffF[(size_t)g * FBK + tid];
            growF[tid + 512] = goffF[(size_t)g * FBK + tid + 512];
            __syncthreads();
            const size_t gb = (size_t)g * GSEG;
            for (int k = 0; k < 6; ++k) {
                int j0 = (tid + 512 * k) * 4;
                const ushort4 lv4 = *(const ushort4*)&lvF[gb + j0];
                const ushort4 b4 = *(const ushort4*)&bidxF[gb + j0];
                finterm[growF[b4.x] + j0 + 0] = pwin[h * 4096 + lv4.x];
                finterm[growF[b4.y] + j0 + 1] = pwin[h * 4096 + lv4.y];
                finterm[growF[b4.z] + j0 + 2] = pwin[h * 4096 + lv4.z];
                finterm[growF[b4.w] + j0 + 3] = pwin[h * 4096 + lv4.w];
            }
            __syncthreads();
        }
    }
}

extern "C" void kernel_launch(void* const* d_in, const int* in_sizes, int n_in,
                              void* d_out, int out_size, void* d_ws, size_t ws_size,
                              hipStream_t stream) {
    const float* llr        = (const float*)d_in[0];
    const int*   var_idx    = (const int*)d_in[1];   (void)var_idx;   // implicit e/3
    const int*   chk_idx    = (const int*)d_in[2];
    const float* beta       = (const float*)d_in[3];
    const float* alpha      = (const float*)d_in[4];
    const float* thresholds = (const float*)d_in[5];
    float* out = (float*)d_out;

    // workspace layout (~215 MB of 256 MiB; im2 aliases im1 — im1 dead after place1)
    char* wsb = (char*)d_ws;
    float*    finterm   = (float*)(wsb + 0);                  // 25165824
    uint16_t* f2pos     = (uint16_t*)(wsb + 25165824);        // 12582912
    uint16_t* lvF       = (uint16_t*)(wsb + 37748736);        // 12582912
    uint16_t* bidxF     = (uint16_t*)(wsb + 50331648);        // 12582912
    uint16_t* lposB     = (uint16_t*)(wsb + 62914560);        // 12582912
    uint16_t* b2pos     = (uint16_t*)(wsb + 75497472);        // 12582912
    uint8_t*  bidxB     = (uint8_t*)(wsb + 88080384);         // 6291456
    uint8_t*  binterm   = (uint8_t*)(wsb + 94371840);         // 6291456
    uint32_t* einfo     = (uint32_t*)(wsb + 100663296);       // 4194304
    uint32_t* chk_edges = (uint32_t*)(wsb + 104857600);       // 25165824
    uint32_t* im1_e     = (uint32_t*)(wsb + 130023424);       // 25165824
    uint16_t* im1_c     = (uint16_t*)(wsb + 155189248);       // 12582912
    uint32_t* im2_pay   = im1_e;                              // alias (im1 dead)
    uint16_t* im2_el    = im1_c;                              // alias
    uint8_t*  f1rank    = (uint8_t*)(wsb + 167772160);        // 6291456
    uint8_t*  b1rank    = (uint8_t*)(wsb + 174063616);        // 6291456
    uint32_t* runcntF   = (uint32_t*)(wsb + 180355072);       // 2097152
    uint32_t* f1base    = (uint32_t*)(wsb + 182452224);       // 2097152
    uint32_t* runcntB   = (uint32_t*)(wsb + 184549376);       // 1048576
    uint32_t* b1base    = (uint32_t*)(wsb + 185597952);       // 1048576
    uint32_t* goffF     = (uint32_t*)(wsb + 186646528);       // 2097152
    uint32_t* goffB     = (uint32_t*)(wsb + 188743680);       // 1048576
    uint32_t* dest      = (uint32_t*)(wsb + 189792256);       // 25165824
    uint32_t* gcur      = (uint32_t*)(wsb + 214958080);       // 4096
    uint32_t* gcurA     = gcur;
    uint32_t* gcurB     = gcur + 512;

    initcur_kernel<<<2, 512, 0, stream>>>(gcur);
    bin1_kernel<<<NBLK, 512, 0, stream>>>(chk_idx, gcurA, im1_e, im1_c);
    place1_kernel<<<PBK, 512, 0, stream>>>(im1_e, im1_c, chk_edges, b1rank, runcntB);
    bin2_kernel<<<NBLK, 512, 0, stream>>>(chk_edges, gcurB, im2_pay, im2_el);
    place2_kernel<<<FG, 512, 0, stream>>>(im2_pay, im2_el, dest, f1rank, runcntF);
    scanF_kernel<<<2, 512, 0, stream>>>(runcntF, f1base);
    fb_kernel<<<FG, 512, 0, stream>>>(dest, f1rank, runcntF, f1base, goffF, f2pos, bidxF, lvF);
    scanB_kernel<<<1, 256, 0, stream>>>(runcntB, b1base);
    bb_kernel<<<FBK, 512, 0, stream>>>(chk_edges, b1rank, runcntB, b1base, goffB, b2pos, bidxB, lposB);
    // seed: finterm <- llr (v2c_0) via forward permute (mode 1)
    var_kernel<<<VBK, 512, 0, stream>>>(llr, binterm, b2pos, lvF, bidxF, goffF,
                                        finterm, thresholds, 0, 1, out);

    for (int t = 0; t < TT; ++t) {
        check_kernel<<<FBK, 256, 0, stream>>>(finterm, f2pos, einfo, lposB, bidxB, goffB,
                                              binterm, beta, alpha, thresholds, t);
        var_kernel<<<VBK, 512, 0, stream>>>(llr, binterm, b2pos, lvF, bidxF, goffF,
                                            finterm, thresholds, t,
                                            (t == TT - 1) ? 2 : 0, out);
    }
}